// Round 4
// baseline (371.037 us; speedup 1.0000x reference)
//
#include <hip/hip_runtime.h>
#include <math.h>

#define IMG_H 1024
#define IMG_W 1024
#define OUT_H 1025
#define OUT_W 1025
#define NIMG  16
#define TOTAL (NIMG * OUT_H * OUT_W)

// No-LDS, no-barrier, no-loop design: each thread owns 4 px of one output row.
// 1025 rows x 4 wave-segments (256 px each) + a 17-wave strip for column 1024.
#define NTHREADS   256
#define ROW_TASKS  (OUT_H * 4)             // 4100 main wave-tasks per image
#define EDGE_TASKS 17                      // j = 1024 column strip (64 rows/wave)
#define NTASKS     (ROW_TASKS + EDGE_TASKS)       // 4117
#define NBLOCKS    ((NTASKS + 3) / 4)             // 1030 blocks (4 waves each)

// Map composed-reflect-padded row/col index k in [0,1026] to source image index.
__device__ __forceinline__ int refl(int k) {
    if (k >= 2) return (k <= 1025) ? (k - 2) : 1022;
    return k;
}

// Generic sobel at output (i,j) — exact f32 op order (bit-matched np, verified R0-R3).
__device__ __forceinline__ void sobel_generic(const float* __restrict__ img, int i, int j,
                                              float& gx, float& gy) {
    int r0 = refl(i), r1 = refl(i + 1), r2 = refl(i + 2);
    int c0 = refl(j), c1 = refl(j + 1), c2 = refl(j + 2);
    const float* p0 = img + r0 * IMG_W;
    const float* p1 = img + r1 * IMG_W;
    const float* p2 = img + r2 * IMG_W;
    float v00 = p0[c0], v01 = p0[c1], v02 = p0[c2];
    float v10 = p1[c0],               v12 = p1[c2];
    float v20 = p2[c0], v21 = p2[c1], v22 = p2[c2];

    float t = -v00;
    t = __fadd_rn(t, v02);
    t = __fadd_rn(t, -2.0f * v10);
    t = __fadd_rn(t, 2.0f * v12);
    t = __fadd_rn(t, -v20);
    gx = __fadd_rn(t, v22);

    t = -v00;
    t = __fadd_rn(t, -2.0f * v01);
    t = __fadd_rn(t, -v02);
    t = __fadd_rn(t, v20);
    t = __fadd_rn(t, 2.0f * v21);
    gy = __fadd_rn(t, v22);
}

// Exact reference binning (double atan2 -> f32 chain). Bit-matched np (R1).
// COLD: only hit in a ~1e-4-wide guard band. noinline keeps the f64 code in
// one outlined copy so its register pressure never touches the hot path.
__device__ __attribute__((noinline)) int classify_slow(float gx, float gy) {
    float t = (float)atan2((double)gx, (double)gy);
    float deg = __fmul_rn(t, (float)(180.0 / M_PI));
    float th = __fadd_rn(deg, 90.0f);
    th = fmodf(th, 180.0f);
    if (th < 0.0f) th += 180.0f;
    if (th < 22.5f || th >= 157.5f) return 0;
    if (th < 67.5f) return 1;
    if (th < 112.5f) return 2;
    return 3;
}

// Fast binning: sign + ratio comparisons with guard band (bit-matched np, R2/R3).
__device__ __forceinline__ int classify(float gx, float gy) {
    float ax = fabsf(gx), ay = fabsf(gy);
    const float T22_LO = 0.414172141e0f;
    const float T22_HI = 0.414254984e0f;
    const float T67_LO = 2.413972141e0f;
    const float T67_HI = 2.414454984e0f;

    if (ax <= ay * T22_LO) return 2;                  // (0,0) lands here: bin 2
    if (ax >= ay * T67_HI) return 0;
    if (ax >= ay * T22_HI && ax <= ay * T67_LO) {
        unsigned s = (__float_as_uint(gx) ^ __float_as_uint(gy)) >> 31;
        return s ? 1 : 3;
    }
    return classify_slow(gx, gy);
}

__device__ __forceinline__ float mag(float gx, float gy) {
    return __fsqrt_rn(__fadd_rn(__fmul_rn(gx, gx), __fmul_rn(gy, gy)));
}

// g and bin at output (y,x); sentinel (-1, 255) outside the grid (== zero-pad
// semantics: bin 255 never matches a real bin, so it contributes 0 to NMS).
__device__ __forceinline__ void gb_at(const float* __restrict__ img, int y, int x,
                                      float& g, unsigned& b) {
    if (y >= 0 && y < OUT_H && x >= 0 && x < OUT_W) {
        float gx, gy;
        sobel_generic(img, y, x, gx, gy);
        g = mag(gx, gy);
        b = (unsigned)classify(gx, gy);
    } else {
        g = -1.0f;
        b = 255u;
    }
}

// Full generic pixel (boundary rows/cols): center + 2 bin-directed neighbors.
__device__ __forceinline__ float px_generic(const float* __restrict__ img, int y, int x) {
    float gx, gy;
    sobel_generic(img, y, x, gx, gy);
    float    gc = mag(gx, gy);
    unsigned bc = (unsigned)classify(gx, gy);
    int dy = (bc == 0u) ? 0 : 1;
    int dx = (bc == 0u) ? 1 : (bc == 1u) ? -1 : (bc == 2u) ? 0 : 1;
    float n1g, n2g; unsigned n1b, n2b;
    gb_at(img, y + dy, x + dx, n1g, n1b);
    gb_at(img, y - dy, x - dx, n2g, n2b);
    float nmax = 0.0f;
    if (n1b == bc && n1g > nmax) nmax = n1g;
    if (n2b == bc && n2g > nmax) nmax = n2g;
    return (gc >= nmax) ? gc : 0.0f;
}

__device__ __forceinline__ void store_px(float* __restrict__ out, size_t o, float e) {
    out[o]                       = (e >= 50.0f) ? 255.5f : 0.0f;
    out[(size_t)TOTAL + o]       = (e >= 50.0f && e < 100.0f) ? 255.0f : 0.0f;
    out[(size_t)(2 * TOTAL) + o] = (e >= 100.0f) ? 255.0f : 0.0f;
}

// launch_bounds(256,4): VGPR cap 128 -> 16 waves/CU; hot path fits, any spill
// lands in the outlined cold atan2 path.
__global__ __launch_bounds__(NTHREADS, 4) void canny_kernel(const float* __restrict__ images,
                                                            float* __restrict__ out) {
    const int tid = threadIdx.x;
    const int w   = tid >> 6;
    const int L   = tid & 63;
    const int id  = blockIdx.x * 4 + w;
    if (id >= NTASKS) return;

    const int img_i = blockIdx.y;
    const float* img = images + (size_t)img_i * IMG_H * IMG_W;

    if (id < ROW_TASKS) {
        const int y   = id >> 2;          // block = one full output row (4 segs)
        const int seg = id & 3;
        const int j0  = seg * 256 + 4 * L;   // this thread's 4 px: j0..j0+3

        float e0, e1, e2, e3;
        const bool fast = (y >= 3 && y <= 1022 && j0 >= 4 && j0 <= 1016);
        if (fast) {
            // ---- 15 independent coalesced float4 loads: rows y-3..y+1, cols j0-4..j0+7
            float R[5][12];
            #pragma unroll
            for (int r = 0; r < 5; ++r) {
                const float* rp = img + (size_t)(y - 3 + r) * IMG_W + (j0 - 4);
                *(float4*)&R[r][0] = *(const float4*)rp;
                *(float4*)&R[r][4] = *(const float4*)(rp + 4);
                *(float4*)&R[r][8] = *(const float4*)(rp + 8);
            }

            // ---- 18 g/bin values in registers: g rows y-1..y+1 (a=0..2),
            //      g cols j0-1..j0+4 (u=0..5). Input col c maps to R idx c-(j0-4).
            float    G[3][6];
            unsigned B[3][6];
            #pragma unroll
            for (int a = 0; a < 3; ++a) {
                #pragma unroll
                for (int u = 0; u < 6; ++u) {
                    float v00 = R[a][u + 1],     v01 = R[a][u + 2],     v02 = R[a][u + 3];
                    float v10 = R[a + 1][u + 1],                        v12 = R[a + 1][u + 3];
                    float v20 = R[a + 2][u + 1], v21 = R[a + 2][u + 2], v22 = R[a + 2][u + 3];

                    float s = -v00;
                    s = __fadd_rn(s, v02);
                    s = __fadd_rn(s, -2.0f * v10);
                    s = __fadd_rn(s, 2.0f * v12);
                    s = __fadd_rn(s, -v20);
                    float gx = __fadd_rn(s, v22);

                    s = -v00;
                    s = __fadd_rn(s, -2.0f * v01);
                    s = __fadd_rn(s, -v02);
                    s = __fadd_rn(s, v20);
                    s = __fadd_rn(s, 2.0f * v21);
                    float gy = __fadd_rn(s, v22);

                    G[a][u] = mag(gx, gy);
                    B[a][u] = (unsigned)classify(gx, gy);
                }
            }

            // ---- NMS, static-index 4-way selects (no runtime array indexing).
            // bin0:(dy 0,dx 1)  bin1:(1,-1)  bin2:(1,0)  bin3:(1,1); n1=+d, n2=-d.
            float ee[4];
            #pragma unroll
            for (int p = 0; p < 4; ++p) {
                float    gc = G[1][p + 1];
                unsigned bc = B[1][p + 1];
                float    n1g = (bc == 0u) ? G[1][p + 2] : (bc == 1u) ? G[2][p]
                             : (bc == 2u) ? G[2][p + 1] : G[2][p + 2];
                unsigned n1b = (bc == 0u) ? B[1][p + 2] : (bc == 1u) ? B[2][p]
                             : (bc == 2u) ? B[2][p + 1] : B[2][p + 2];
                float    n2g = (bc == 0u) ? G[1][p]     : (bc == 1u) ? G[0][p + 2]
                             : (bc == 2u) ? G[0][p + 1] : G[0][p];
                unsigned n2b = (bc == 0u) ? B[1][p]     : (bc == 1u) ? B[0][p + 2]
                             : (bc == 2u) ? B[0][p + 1] : B[0][p];
                float nmax = 0.0f;
                if (n1b == bc && n1g > nmax) nmax = n1g;
                if (n2b == bc && n2g > nmax) nmax = n2g;
                ee[p] = (gc >= nmax) ? gc : 0.0f;
            }
            e0 = ee[0]; e1 = ee[1]; e2 = ee[2]; e3 = ee[3];
        } else {
            // Boundary rows / edge lanes: per-pixel generic (reflection + pad).
            e0 = px_generic(img, y, j0);
            e1 = px_generic(img, y, j0 + 1);
            e2 = px_generic(img, y, j0 + 2);
            e3 = px_generic(img, y, j0 + 3);
        }

        size_t o = ((size_t)(img_i * OUT_H + y)) * OUT_W + j0;
        store_px(out, o,     e0);
        store_px(out, o + 1, e1);
        store_px(out, o + 2, e2);
        store_px(out, o + 3, e3);
    } else {
        // j = 1024 column strip: one px per lane, 64 rows per wave.
        const int k = id - ROW_TASKS;
        const int y = k * 64 + L;
        if (y < OUT_H) {
            float e = px_generic(img, y, 1024);
            size_t o = ((size_t)(img_i * OUT_H + y)) * OUT_W + 1024;
            store_px(out, o, e);
        }
    }
}

extern "C" void kernel_launch(void* const* d_in, const int* in_sizes, int n_in,
                              void* d_out, int out_size, void* d_ws, size_t ws_size,
                              hipStream_t stream) {
    const float* images = (const float*)d_in[0];
    float* outp = (float*)d_out;
    dim3 grid(NBLOCKS, NIMG, 1);
    canny_kernel<<<grid, NTHREADS, 0, stream>>>(images, outp);
}

// Round 5
// 328.034 us; speedup vs baseline: 1.1311x; 1.1311x over previous
//
#include <hip/hip_runtime.h>
#include <math.h>

#define IMG_H 1024
#define IMG_W 1024
#define OUT_H 1025
#define OUT_W 1025
#define NIMG  16
#define TOTAL (NIMG * OUT_H * OUT_W)

// Wave-autonomous version of the verified 16x64-tile 2-phase kernel:
// each WAVE owns one tile + a private LDS slab; NO __syncthreads anywhere
// (in-wave ds_write -> ds_read ordering is compiler-inserted lgkmcnt; this
// barrier-free in-wave LDS pattern passed verification in R3).
#define TILE_W 64
#define TILE_H 16
#define HALO_W 68                 // ox in [tile_ox-2, tile_ox+65]
#define HALO_H 18                 // oy in [tile_oy-1, tile_oy+16]
#define NQX    17                 // 68/4 x-quads per halo row
#define NQUAD  (HALO_H * NQX)     // 306 quads per tile
#define NPASS  5                  // ceil(306/64) passes per wave
#define WPB    4                  // independent waves (tiles) per block
#define NTHREADS 256
#define XTILES 17
#define YTILESN 65
#define NTASKS (XTILES * YTILESN * NIMG)   // 17680 wave-tasks
#define NBLOCKS (NTASKS / WPB)             // 4420 (exact)

// Map bp (double-reflect-padded) row/col index k in [0,1026] to source image index.
__device__ __forceinline__ int refl(int k) {
    if (k >= 2) return (k <= 1025) ? (k - 2) : 1022;
    return k;
}

// Generic sobel at output (i,j) — exact f32 op order (bit-matched np, R0-R4).
__device__ __forceinline__ void sobel_generic(const float* __restrict__ img, int i, int j,
                                              float& gx, float& gy) {
    int r0 = refl(i), r1 = refl(i + 1), r2 = refl(i + 2);
    int c0 = refl(j), c1 = refl(j + 1), c2 = refl(j + 2);
    const float* p0 = img + r0 * IMG_W;
    const float* p1 = img + r1 * IMG_W;
    const float* p2 = img + r2 * IMG_W;
    float v00 = p0[c0], v01 = p0[c1], v02 = p0[c2];
    float v10 = p1[c0],               v12 = p1[c2];
    float v20 = p2[c0], v21 = p2[c1], v22 = p2[c2];

    float t = -v00;
    t = __fadd_rn(t, v02);
    t = __fadd_rn(t, -2.0f * v10);
    t = __fadd_rn(t, 2.0f * v12);
    t = __fadd_rn(t, -v20);
    gx = __fadd_rn(t, v22);

    t = -v00;
    t = __fadd_rn(t, -2.0f * v01);
    t = __fadd_rn(t, -v02);
    t = __fadd_rn(t, v20);
    t = __fadd_rn(t, 2.0f * v21);
    gy = __fadd_rn(t, v22);
}

// Exact reference binning (double atan2 -> f32 chain). Bit-matched np (R1).
// COLD: only hit in a ~1e-4-wide guard band; outlined so its f64 register
// pressure never touches the hot path.
__device__ __attribute__((noinline)) int classify_slow(float gx, float gy) {
    float t = (float)atan2((double)gx, (double)gy);
    float deg = __fmul_rn(t, (float)(180.0 / M_PI));
    float th = __fadd_rn(deg, 90.0f);
    th = fmodf(th, 180.0f);
    if (th < 0.0f) th += 180.0f;
    if (th < 22.5f || th >= 157.5f) return 0;
    if (th < 67.5f) return 1;
    if (th < 112.5f) return 2;
    return 3;
}

// Fast binning: sign + ratio comparisons with guard band (bit-matched np, R2/R3).
__device__ __forceinline__ int classify(float gx, float gy) {
    float ax = fabsf(gx), ay = fabsf(gy);
    const float T22_LO = 0.414172141e0f;
    const float T22_HI = 0.414254984e0f;
    const float T67_LO = 2.413972141e0f;
    const float T67_HI = 2.414454984e0f;

    if (ax <= ay * T22_LO) return 2;                  // (0,0) lands here: bin 2
    if (ax >= ay * T67_HI) return 0;
    if (ax >= ay * T22_HI && ax <= ay * T67_LO) {
        unsigned s = (__float_as_uint(gx) ^ __float_as_uint(gy)) >> 31;
        return s ? 1 : 3;
    }
    return classify_slow(gx, gy);
}

__device__ __forceinline__ float mag(float gx, float gy) {
    return __fsqrt_rn(__fadd_rn(__fmul_rn(gx, gx), __fmul_rn(gy, gy)));
}

__device__ __forceinline__ void load6(const float* __restrict__ p, float v[6]) {
    float4 a = *(const float4*)p;        // 16B aligned: col base ≡ 0 (mod 4)
    float2 b = *(const float2*)(p + 4);
    v[0] = a.x; v[1] = a.y; v[2] = a.z; v[3] = a.w; v[4] = b.x; v[5] = b.y;
}

// launch_bounds(256,5): VGPR cap ~102; LDS (24.5KB/block) allows 6 blocks/CU
// -> 24 waves/CU; 5 waves/EU cap (20/CU) is the consistent budget.
__global__ __launch_bounds__(NTHREADS, 5) void canny_kernel(const float* __restrict__ images,
                                                            float* __restrict__ out) {
    // Per-wave private slabs: no cross-wave LDS sharing -> no barrier needed.
    __shared__ float    g_all[WPB][HALO_H * HALO_W];   // 4 x 4896 B
    __shared__ unsigned b_all[WPB][HALO_H * NQX];      // 4 x 1224 B  (total 24480 B)

    const int tid = threadIdx.x;
    const int w   = tid >> 6;
    const int L   = tid & 63;

    const int task  = blockIdx.x * WPB + w;
    const int img_i = task / (XTILES * YTILESN);
    const int rem   = task - img_i * (XTILES * YTILESN);
    const int ty    = rem / XTILES;
    const int tx    = rem - ty * XTILES;

    const int tile_ox = tx * TILE_W;
    const int tile_oy = ty * TILE_H;
    const float* img = images + (size_t)img_i * IMG_H * IMG_W;

    float*    g_s = g_all[w];
    unsigned* b_u = b_all[w];

    // ---- Phase 1: g + bin for the 18x68 halo, 5 passes of 64 quads ----
    // Double-buffered register prefetch: pass p+1's rows load while pass p computes.
    float A[3][6], Bf[3][6];

    // prologue: prefetch pass 0
    {
        int q  = L;
        int hy = q / NQX, qx = q - hy * NQX;
        int oy = tile_oy + hy - 1, ox0 = tile_ox + qx * 4 - 2;
        if (oy >= 2 && oy <= 1023 && ox0 >= 2 && ox0 <= 1020) {
            const float* r0p = img + (size_t)(oy - 2) * IMG_W + (ox0 - 2);
            load6(r0p,             A[0]);
            load6(r0p + IMG_W,     A[1]);
            load6(r0p + 2 * IMG_W, A[2]);
        }
    }

    #pragma unroll
    for (int p = 0; p < NPASS; ++p) {
        // prefetch pass p+1
        if (p + 1 < NPASS) {
            int q  = (p + 1) * 64 + L;
            int hy = q / NQX, qx = q - hy * NQX;
            int oy = tile_oy + hy - 1, ox0 = tile_ox + qx * 4 - 2;
            if (q < NQUAD && oy >= 2 && oy <= 1023 && ox0 >= 2 && ox0 <= 1020) {
                const float* r0p = img + (size_t)(oy - 2) * IMG_W + (ox0 - 2);
                load6(r0p,             Bf[0]);
                load6(r0p + IMG_W,     Bf[1]);
                load6(r0p + 2 * IMG_W, Bf[2]);
            }
        }

        // compute pass p
        int q = p * 64 + L;
        if (q < NQUAD) {
            int hy = q / NQX, qx = q - hy * NQX;
            int oy = tile_oy + hy - 1, ox0 = tile_ox + qx * 4 - 2;

            float    gxs[4], gys[4], gq[4];
            unsigned bq[4];

            if (oy >= 2 && oy <= 1023 && ox0 >= 2 && ox0 <= 1020) {
                #pragma unroll
                for (int pp = 0; pp < 4; ++pp) {
                    float v00 = A[0][pp], v01 = A[0][pp + 1], v02 = A[0][pp + 2];
                    float v10 = A[1][pp],                     v12 = A[1][pp + 2];
                    float v20 = A[2][pp], v21 = A[2][pp + 1], v22 = A[2][pp + 2];

                    float s = -v00;
                    s = __fadd_rn(s, v02);
                    s = __fadd_rn(s, -2.0f * v10);
                    s = __fadd_rn(s, 2.0f * v12);
                    s = __fadd_rn(s, -v20);
                    float gx = __fadd_rn(s, v22);

                    s = -v00;
                    s = __fadd_rn(s, -2.0f * v01);
                    s = __fadd_rn(s, -v02);
                    s = __fadd_rn(s, v20);
                    s = __fadd_rn(s, 2.0f * v21);
                    float gy = __fadd_rn(s, v22);

                    gxs[pp] = gx;
                    gys[pp] = gy;
                    gq[pp]  = mag(gx, gy);
                }
            } else {
                #pragma unroll
                for (int pp = 0; pp < 4; ++pp) {
                    int ox = ox0 + pp;
                    if (oy >= 0 && oy < OUT_H && ox >= 0 && ox < OUT_W) {
                        float gx, gy;
                        sobel_generic(img, oy, ox, gx, gy);
                        gxs[pp] = gx;
                        gys[pp] = gy;
                        gq[pp]  = mag(gx, gy);
                    } else {
                        gxs[pp] = 0.0f;
                        gys[pp] = 1.0f;
                        gq[pp]  = -1.0f;      // sentinel: invalid halo px
                    }
                }
            }

            // classify after input rows are dead (cold f64-atan2 guard band)
            #pragma unroll
            for (int pp = 0; pp < 4; ++pp) {
                bq[pp] = (gq[pp] < 0.0f) ? 255u : (unsigned)classify(gxs[pp], gys[pp]);
            }

            int ldoff = hy * HALO_W + qx * 4;            // dword index, multiple of 4
            *(float4*)&g_s[ldoff] = make_float4(gq[0], gq[1], gq[2], gq[3]);
            b_u[hy * NQX + qx] = bq[0] | (bq[1] << 8) | (bq[2] << 16) | (bq[3] << 24);
        }

        // rotate prefetch regs (static indices -> stays in VGPRs)
        if (p + 1 < NPASS) {
            #pragma unroll
            for (int r = 0; r < 3; ++r)
                #pragma unroll
                for (int cc = 0; cc < 6; ++cc)
                    A[r][cc] = Bf[r][cc];
        }
    }

    // ---- Phase 2: NMS + thresholds from this wave's own LDS (no barrier) ----
    const unsigned char* b_s = (const unsigned char*)b_u;
    const int ox = tile_ox + L;                  // lane owns one column
    if (ox < OUT_W) {
        #pragma unroll 4
        for (int k = 0; k < TILE_H; ++k) {
            int oy = tile_oy + k;
            if (oy >= OUT_H) break;

            int hc = (k + 1) * HALO_W + (L + 2);
            float gc = g_s[hc];
            int   bc = b_s[hc];

            int doff = (bc == 0) ? 1
                     : (bc == 1) ? (HALO_W - 1)
                     : (bc == 2) ? HALO_W
                     :             (HALO_W + 1);

            float nmax = 0.0f;
            float g1 = g_s[hc + doff];
            if (b_s[hc + doff] == bc && g1 > nmax) nmax = g1;
            float g2 = g_s[hc - doff];
            if (b_s[hc - doff] == bc && g2 > nmax) nmax = g2;

            float e = (gc >= nmax) ? gc : 0.0f;

            size_t o = (size_t)(img_i * OUT_H + oy) * OUT_W + ox;
            out[o]                       = (e >= 50.0f) ? 255.5f : 0.0f;
            out[(size_t)TOTAL + o]       = (e >= 50.0f && e < 100.0f) ? 255.0f : 0.0f;
            out[(size_t)(2 * TOTAL) + o] = (e >= 100.0f) ? 255.0f : 0.0f;
        }
    }
}

extern "C" void kernel_launch(void* const* d_in, const int* in_sizes, int n_in,
                              void* d_out, int out_size, void* d_ws, size_t ws_size,
                              hipStream_t stream) {
    const float* images = (const float*)d_in[0];
    float* outp = (float*)d_out;
    dim3 grid(NBLOCKS, 1, 1);
    canny_kernel<<<grid, NTHREADS, 0, stream>>>(images, outp);
}

// Round 6
// 319.770 us; speedup vs baseline: 1.1603x; 1.0258x over previous
//
#include <hip/hip_runtime.h>
#include <math.h>

#define IMG_H 1024
#define IMG_W 1024
#define OUT_H 1025
#define OUT_W 1025
#define NIMG  16
#define TOTAL (NIMG * OUT_H * OUT_W)

#define TILE_W 64
#define TILE_H 16
#define HALO_W 68                 // halo width in px; also b-ring BYTE row stride
#define GSTR   69                 // g_s row stride (padded: keeps 4px/thread phase-2 reads 2-way)
#define HALO_H 18                 // oy in [tile_oy-1, tile_oy+16]
#define NQX    17                 // 68/4 x-quads per halo row
#define NQUAD  (HALO_H * NQX)     // 306
#define NTHREADS 320

// Map bp (double-reflect-padded) row/col index k in [0,1026] to source image index.
__device__ __forceinline__ int refl(int k) {
    if (k >= 2) return (k <= 1025) ? (k - 2) : 1022;
    return k;
}

// Generic sobel at output (i,j) — exact f32 op order (bit-matched np, R0-R5).
__device__ __forceinline__ void sobel_generic(const float* __restrict__ img, int i, int j,
                                              float& gx, float& gy) {
    int r0 = refl(i), r1 = refl(i + 1), r2 = refl(i + 2);
    int c0 = refl(j), c1 = refl(j + 1), c2 = refl(j + 2);
    const float* p0 = img + r0 * IMG_W;
    const float* p1 = img + r1 * IMG_W;
    const float* p2 = img + r2 * IMG_W;
    float v00 = p0[c0], v01 = p0[c1], v02 = p0[c2];
    float v10 = p1[c0],               v12 = p1[c2];
    float v20 = p2[c0], v21 = p2[c1], v22 = p2[c2];

    float t = -v00;
    t = __fadd_rn(t, v02);
    t = __fadd_rn(t, -2.0f * v10);
    t = __fadd_rn(t, 2.0f * v12);
    t = __fadd_rn(t, -v20);
    gx = __fadd_rn(t, v22);

    t = -v00;
    t = __fadd_rn(t, -2.0f * v01);
    t = __fadd_rn(t, -v02);
    t = __fadd_rn(t, v20);
    t = __fadd_rn(t, 2.0f * v21);
    gy = __fadd_rn(t, v22);
}

// Exact reference binning (double atan2 -> f32 chain). Bit-matched np (R1).
// COLD: outlined so the f64 register pressure never touches the hot path.
__device__ __attribute__((noinline)) int classify_slow(float gx, float gy) {
    float t = (float)atan2((double)gx, (double)gy);
    float deg = __fmul_rn(t, (float)(180.0 / M_PI));
    float th = __fadd_rn(deg, 90.0f);
    th = fmodf(th, 180.0f);
    if (th < 0.0f) th += 180.0f;
    if (th < 22.5f || th >= 157.5f) return 0;
    if (th < 67.5f) return 1;
    if (th < 112.5f) return 2;
    return 3;
}

// Fast binning: sign + ratio comparisons with guard band (bit-matched np, R2/R3).
__device__ __forceinline__ int classify(float gx, float gy) {
    float ax = fabsf(gx), ay = fabsf(gy);
    const float T22_LO = 0.414172141e0f;
    const float T22_HI = 0.414254984e0f;
    const float T67_LO = 2.413972141e0f;
    const float T67_HI = 2.414454984e0f;

    if (ax <= ay * T22_LO) return 2;                  // (0,0) lands here: bin 2
    if (ax >= ay * T67_HI) return 0;
    if (ax >= ay * T22_HI && ax <= ay * T67_LO) {
        unsigned s = (__float_as_uint(gx) ^ __float_as_uint(gy)) >> 31;
        return s ? 1 : 3;
    }
    return classify_slow(gx, gy);
}

__device__ __forceinline__ float mag(float gx, float gy) {
    return __fsqrt_rn(__fadd_rn(__fmul_rn(gx, gx), __fmul_rn(gy, gy)));
}

__device__ __forceinline__ void load6(const float* __restrict__ p, float v[6]) {
    float4 a = *(const float4*)p;        // 16B aligned: col base ≡ 0 (mod 4)
    float2 b = *(const float2*)(p + 4);
    v[0] = a.x; v[1] = a.y; v[2] = a.z; v[3] = a.w; v[4] = b.x; v[5] = b.y;
}

// NMS for tile-local px (r,c) from the LDS halo. Identical arithmetic to the
// verified champion (g stride GSTR, b stride HALO_W handled separately).
__device__ __forceinline__ float nms_px(const float* __restrict__ g_s,
                                        const unsigned char* __restrict__ b_s,
                                        int r, int c) {
    int hg = (r + 1) * GSTR   + (c + 2);
    int hb = (r + 1) * HALO_W + (c + 2);
    float gc = g_s[hg];
    int   bc = b_s[hb];
    int dy = (bc == 0) ? 0 : 1;
    int dx = (bc == 1) ? -1 : ((bc == 2) ? 0 : 1);
    int og = dy * GSTR   + dx;
    int ob = dy * HALO_W + dx;
    float nmax = 0.0f;
    float g1 = g_s[hg + og];
    if (b_s[hb + ob] == bc && g1 > nmax) nmax = g1;
    float g2 = g_s[hg - og];
    if (b_s[hb - ob] == bc && g2 > nmax) nmax = g2;
    return (gc >= nmax) ? gc : 0.0f;
}

__global__ __launch_bounds__(NTHREADS) void canny_kernel(const float* __restrict__ images,
                                                         float* __restrict__ out) {
    __shared__ float    g_s[HALO_H * GSTR];      // 4968 B
    __shared__ unsigned b_u[HALO_H * NQX];       // 1224 B

    const int tile_ox = blockIdx.x * TILE_W;
    const int tile_oy = blockIdx.y * TILE_H;
    const int n       = blockIdx.z;
    const float* img = images + (size_t)n * IMG_H * IMG_W;
    const int t = threadIdx.x;

    // ---- Phase 1: g + bin for the 18x68 halo, one x-quad per thread ----
    if (t < NQUAD) {
        int hy  = t / NQX;
        int qx  = t - hy * NQX;
        int oy  = tile_oy + hy - 1;
        int ox0 = tile_ox + qx * 4 - 2;   // ≡ 2 (mod 4)

        float    gxs[4], gys[4], gq[4];
        unsigned bq[4];

        if (oy >= 2 && oy <= 1023 && ox0 >= 2 && ox0 <= 1020) {
            // Interior fast path: rows oy-2..oy, cols ox0-2..ox0+3, no reflection.
            const float* r0p = img + (size_t)(oy - 2) * IMG_W + (ox0 - 2);
            float R0[6], R1[6], R2[6];
            load6(r0p, R0);
            load6(r0p + IMG_W, R1);
            load6(r0p + 2 * IMG_W, R2);
            #pragma unroll
            for (int p = 0; p < 4; p++) {
                float v00 = R0[p], v01 = R0[p + 1], v02 = R0[p + 2];
                float v10 = R1[p],                  v12 = R1[p + 2];
                float v20 = R2[p], v21 = R2[p + 1], v22 = R2[p + 2];

                float s = -v00;
                s = __fadd_rn(s, v02);
                s = __fadd_rn(s, -2.0f * v10);
                s = __fadd_rn(s, 2.0f * v12);
                s = __fadd_rn(s, -v20);
                float gx = __fadd_rn(s, v22);

                s = -v00;
                s = __fadd_rn(s, -2.0f * v01);
                s = __fadd_rn(s, -v02);
                s = __fadd_rn(s, v20);
                s = __fadd_rn(s, 2.0f * v21);
                float gy = __fadd_rn(s, v22);

                gxs[p] = gx; gys[p] = gy;
                gq[p]  = mag(gx, gy);
            }
        } else {
            // Boundary quad: per-pixel generic (reflection + bounds).
            #pragma unroll
            for (int p = 0; p < 4; p++) {
                int ox = ox0 + p;
                if (oy >= 0 && oy < OUT_H && ox >= 0 && ox < OUT_W) {
                    float gx, gy;
                    sobel_generic(img, oy, ox, gx, gy);
                    gxs[p] = gx; gys[p] = gy;
                    gq[p]  = mag(gx, gy);
                } else {
                    gxs[p] = 0.0f; gys[p] = 1.0f;
                    gq[p]  = -1.0f;      // sentinel: invalid halo px
                }
            }
        }

        // Classify after input rows are dead (cold f64-atan2 guard band).
        #pragma unroll
        for (int p = 0; p < 4; p++) {
            bq[p] = (gq[p] < 0.0f) ? 255u : (unsigned)classify(gxs[p], gys[p]);
        }

        int goff = hy * GSTR + qx * 4;      // scalar writes (GSTR odd -> no b128)
        g_s[goff + 0] = gq[0];
        g_s[goff + 1] = gq[1];
        g_s[goff + 2] = gq[2];
        g_s[goff + 3] = gq[3];
        b_u[hy * NQX + qx] = bq[0] | (bq[1] << 8) | (bq[2] << 16) | (bq[3] << 24);
    }
    __syncthreads();

    // ---- Phase 2: NMS + thresholds; VECTOR (dwordx4) stores ----
    const unsigned char* b_s = (const unsigned char*)b_u;

    if (tile_ox + TILE_W <= OUT_W) {
        // Interior x-tiles: 4 px per thread, 16B-aligned float4 stores.
        // Row stride 1025 is odd -> aligned group origin a varies per row.
        if (t < 256) {
            int r  = t >> 4;
            int k  = t & 15;
            int oy = tile_oy + r;
            if (oy < OUT_H) {
                size_t rowbase = (size_t)(n * OUT_H + oy) * OUT_W + tile_ox;
                int a = (int)((4u - ((unsigned)rowbase & 3u)) & 3u);
                if (k < 15) {
                    int c0 = a + 4 * k;                       // cols c0..c0+3
                    float e0 = nms_px(g_s, b_s, r, c0);
                    float e1 = nms_px(g_s, b_s, r, c0 + 1);
                    float e2 = nms_px(g_s, b_s, r, c0 + 2);
                    float e3 = nms_px(g_s, b_s, r, c0 + 3);

                    float4 P0 = make_float4(e0 >= 50.0f ? 255.5f : 0.0f,
                                            e1 >= 50.0f ? 255.5f : 0.0f,
                                            e2 >= 50.0f ? 255.5f : 0.0f,
                                            e3 >= 50.0f ? 255.5f : 0.0f);
                    float4 P1 = make_float4((e0 >= 50.0f && e0 < 100.0f) ? 255.0f : 0.0f,
                                            (e1 >= 50.0f && e1 < 100.0f) ? 255.0f : 0.0f,
                                            (e2 >= 50.0f && e2 < 100.0f) ? 255.0f : 0.0f,
                                            (e3 >= 50.0f && e3 < 100.0f) ? 255.0f : 0.0f);
                    float4 P2 = make_float4(e0 >= 100.0f ? 255.0f : 0.0f,
                                            e1 >= 100.0f ? 255.0f : 0.0f,
                                            e2 >= 100.0f ? 255.0f : 0.0f,
                                            e3 >= 100.0f ? 255.0f : 0.0f);

                    size_t o = rowbase + c0;                  // (o & 3) == 0 -> 16B aligned
                    *(float4*)(out + o)                   = P0;
                    *(float4*)(out + (size_t)TOTAL + o)   = P1;
                    *(float4*)(out + (size_t)(2 * TOTAL) + o) = P2;
                } else {
                    // Ragged px of this row: head cols 0..a-1, tail cols a+60..63.
                    #pragma unroll
                    for (int j = 0; j < 4; j++) {
                        int c = (j < a) ? j : (60 + j);
                        float e = nms_px(g_s, b_s, r, c);
                        size_t o = rowbase + c;
                        out[o]                       = (e >= 50.0f) ? 255.5f : 0.0f;
                        out[(size_t)TOTAL + o]       = (e >= 50.0f && e < 100.0f) ? 255.0f : 0.0f;
                        out[(size_t)(2 * TOTAL) + o] = (e >= 100.0f) ? 255.0f : 0.0f;
                    }
                }
            }
        }
    } else {
        // Last x-tile (tile_ox = 1024): only col 0 in range -> scalar path.
        #pragma unroll
        for (int q = 0; q < 4; q++) {
            int p = t + NTHREADS * q;
            if (p >= TILE_W * TILE_H) break;
            int r = p >> 6, c = p & 63;
            int oy = tile_oy + r, ox = tile_ox + c;
            if (oy >= OUT_H || ox >= OUT_W) continue;
            float e = nms_px(g_s, b_s, r, c);
            size_t o = (size_t)(n * OUT_H + oy) * OUT_W + ox;
            out[o]                       = (e >= 50.0f) ? 255.5f : 0.0f;
            out[(size_t)TOTAL + o]       = (e >= 50.0f && e < 100.0f) ? 255.0f : 0.0f;
            out[(size_t)(2 * TOTAL) + o] = (e >= 100.0f) ? 255.0f : 0.0f;
        }
    }
}

extern "C" void kernel_launch(void* const* d_in, const int* in_sizes, int n_in,
                              void* d_out, int out_size, void* d_ws, size_t ws_size,
                              hipStream_t stream) {
    const float* images = (const float*)d_in[0];
    float* outp = (float*)d_out;
    dim3 grid((OUT_W + TILE_W - 1) / TILE_W,   // 17
              (OUT_H + TILE_H - 1) / TILE_H,   // 65
              NIMG);                            // 16
    canny_kernel<<<grid, NTHREADS, 0, stream>>>(images, outp);
}